// Round 9
// baseline (155.669 us; speedup 1.0000x reference)
//
#include <hip/hip_runtime.h>
#include <math.h>

typedef _Float16 f16;
typedef _Float16 f16x4 __attribute__((ext_vector_type(4)));
typedef _Float16 f16x8 __attribute__((ext_vector_type(8)));
typedef float f32x16 __attribute__((ext_vector_type(16)));

#define MFMA_ __builtin_amdgcn_mfma_f32_32x32x16_f16
#define SLOPE_ 0.2f

constexpr int kB = 64, kT = 512, kD = 8, kH = 128, kE = 96;
constexpr int kFG = 145, kTM = 510, kN = kB * kTM;   // 32640 = 255*128
constexpr int kFCB = kN / 128;                       // 255 fc blocks

// k-permutation absorbed into weight images so next-layer B-fragments are the
// held C/D quads verbatim. For k<128 this swaps bits 2<->3 region-wise; any
// aligned 4-col group maps to 4 CONSECUTIVE dest cols (j&3 preserved).
__device__ __forceinline__ int pif(int k) {
  if (k >= 128) return k;
  int c = k >> 4, s = (k >> 3) & 1, j = k & 7;
  return ((c >> 1) << 5) | ((c & 1) << 4) | ((j >> 2) << 3) | (s << 2) | (j & 3);
}

// fragment-linear images: frag f = 64 lanes x 16 B contiguous.
__device__ __forceinline__ f16x8 gfrag(const f16* img, int f, int lane) {
  return *(const f16x8*)(img + (size_t)f*512 + lane*8);
}

// async global->LDS DMA, 16B per lane (wave-uniform LDS base + lane*16).
__device__ __forceinline__ void lds_dma16(const f16* g, f16* l) {
  __builtin_amdgcn_global_load_lds(
      (const __attribute__((address_space(1))) void*)g,
      (__attribute__((address_space(3))) void*)l, 16, 0, 0);
}

__device__ __forceinline__ f16x8 cvt8(float4 a, float4 b) {
  f16x8 v;
  v[0]=(f16)a.x; v[1]=(f16)a.y; v[2]=(f16)a.z; v[3]=(f16)a.w;
  v[4]=(f16)b.x; v[5]=(f16)b.y; v[6]=(f16)b.z; v[7]=(f16)b.w;
  return v;
}

// ========= fc-weight pre-convert: f32 row-major -> f16 fragment-linear ======
template<int NF, int SK, int PERM>
__device__ __forceinline__ void cvt_img(const float* __restrict__ src,
                                        f16* __restrict__ dst, int nd,
                                        int t0, int stride) {
  const int per_d = NF * 512;
  for (int e = t0; e < nd * per_d; e += stride) {
    int dd = e / per_d, r = e - dd * per_d;
    int f = r >> 9, l = (r >> 3) & 63, j = r & 7;
    int c = f >> 2, t = f & 3;
    int row = t*32 + (l & 31);
    int col = c*16 + ((l >> 5) << 3) + j;
    if (PERM) col = pif(col);
    dst[e] = (f16)src[((size_t)dd*kH + row)*SK + col];
  }
}

// Small kernel: only what fc_kernel needs, plus w144/logdet init.
__global__ __launch_bounds__(256) void cvt_fc_kernel(
    const float* __restrict__ fcW0, const float* __restrict__ fcW1,
    const float* __restrict__ fcWf, const float* __restrict__ gW0,
    f16* __restrict__ fW0img, f16* __restrict__ fW1img, f16* __restrict__ fWfimg,
    float* __restrict__ w144buf, float* __restrict__ logdet)
{
  const int stride = gridDim.x * 256;
  const int t0 = blockIdx.x*256 + threadIdx.x;
  cvt_img<24, kE , 0>(fcW0, fW0img, 1, t0, stride);
  cvt_img<32, kH , 1>(fcW1, fW1img, 1, t0, stride);
  cvt_img<32, kH , 1>(fcWf, fWfimg, 1, t0, stride);
  for (int i = t0; i < kD*kH; i += stride)
    w144buf[i] = gW0[(size_t)i*kFG + 144];
  if (t0 < kB) logdet[t0] = 0.f;
}

// ===== fused dispatch: blocks 0..254 run fc_mlp; blocks 255..510 convert the
// g-weight images. Conversion now 4-col vectorized: pif maps aligned 4-col
// groups to consecutive dest cols -> float4 loads + single 8B f16x4 stores
// (4x fewer iterations/stores than the scalar scatter). ====================
__global__ __launch_bounds__(256, 2) void fc_cvtg_kernel(
    const float* __restrict__ emb,
    const f16* __restrict__ fW0, const f16* __restrict__ fW1,
    const f16* __restrict__ fWf,
    const float* __restrict__ b0, const float* __restrict__ b1,
    const float* __restrict__ bf, f16* __restrict__ out,
    const float* __restrict__ gW0, const float* __restrict__ gW1,
    const float* __restrict__ gW2,
    const float* __restrict__ gb0, const float* __restrict__ gb1,
    const float* __restrict__ gb2, const float* __restrict__ gWf,
    f16* __restrict__ W0img, f16* __restrict__ W1img, f16* __restrict__ W2img,
    f16* __restrict__ wfimg)
{
  __shared__ f16 wbuf[62*512];                 // fW1 frags 0..31, fWf frags 0..29

  if (blockIdx.x >= kFCB) {
    // ---------------- cvt-g path (no LDS, no barriers) ----------------
    const int t0 = (blockIdx.x - kFCB)*256 + threadIdx.x;
    const int stride = (gridDim.x - kFCB) * 256;

    // W1/W2 main cols 0..127: 4-col groups. kH*kH/4 = 4096 groups per d.
    for (int idx = t0; idx < kD*kH*kH/4; idx += stride) {
      int d = idx >> 12, r = idx & 4095;
      int row = r >> 5, colS = (r & 31) * 4;
      float4 v1 = *(const float4*)(gW1 + ((size_t)d*kH + row)*kH + colS);
      float4 v2 = *(const float4*)(gW2 + ((size_t)d*kH + row)*kH + colS);
      int colD = pif(colS);                    // 4 consecutive dest cols
      int c = colD >> 4, hb = (colD >> 3) & 1, j = colD & 7;
      int e = d*36*512 + (c*4 + (row>>5))*512 + (hb*32 + (row&31))*8 + j;
      f16x4 h1; h1[0]=(f16)v1.x; h1[1]=(f16)v1.y; h1[2]=(f16)v1.z; h1[3]=(f16)v1.w;
      f16x4 h2; h2[0]=(f16)v2.x; h2[1]=(f16)v2.y; h2[2]=(f16)v2.z; h2[3]=(f16)v2.w;
      *(f16x4*)(W1img + e) = h1;
      *(f16x4*)(W2img + e) = h2;
    }
    // W1/W2 slab frags 32..35 (dest cols 128..143): bias at col 128, else 0.
    for (int idx = t0; idx < kD*4*512; idx += stride) {
      int d = idx >> 11, r = idx & 2047;
      int t = r >> 9, l = (r >> 3) & 63, j = r & 7;
      int hb = l >> 5, l31 = l & 31;
      int colD = 128 + hb*8 + j;
      int row = t*32 + l31;
      float v1 = (colD == 128) ? gb1[d*kH + row] : 0.f;
      float v2 = (colD == 128) ? gb2[d*kH + row] : 0.f;
      int e = d*36*512 + (32 + t)*512 + l*8 + j;
      W1img[e] = (f16)v1;
      W2img[e] = (f16)v2;
    }
    // W0 main cols 0..143: 4-col groups (36 per row). Row stride 145 floats
    // -> scalar loads (4B-aligned), still same-cache-line; 8B vector store.
    for (int idx = t0; idx < kD*kH*36; idx += stride) {
      int d = idx / (kH*36), r = idx - d*(kH*36);
      int row = r / 36, colS = (r - row*36) * 4;
      const float* p = gW0 + ((size_t)d*kH + row)*kFG + colS;
      float a0 = p[0], a1 = p[1], a2 = p[2], a3 = p[3];
      int colD = (colS < 128) ? pif(colS) : colS;
      int c = colD >> 4, hb = (colD >> 3) & 1, j = colD & 7;
      int e = d*40*512 + (c*4 + (row>>5))*512 + (hb*32 + (row&31))*8 + j;
      f16x4 h; h[0]=(f16)a0; h[1]=(f16)a1; h[2]=(f16)a2; h[3]=(f16)a3;
      *(f16x4*)(W0img + e) = h;
    }
    // W0 slab frags 36..39 (dest cols 144..159): w144, bias, zeros.
    for (int idx = t0; idx < kD*4*512; idx += stride) {
      int d = idx >> 11, r = idx & 2047;
      int t = r >> 9, l = (r >> 3) & 63, j = r & 7;
      int hb = l >> 5, l31 = l & 31;
      int colD = 144 + hb*8 + j;
      int row = t*32 + l31;
      float v = (colD == 144) ? gW0[((size_t)d*kH + row)*kFG + 144]
              : (colD == 145) ? gb0[d*kH + row] : 0.f;
      int e = d*40*512 + (36 + t)*512 + l*8 + j;
      W0img[e] = (f16)v;
    }
    // wfimg: 8 frags/d, wf in output-row 0 only, pi-ordered cols (tiny).
    for (int e = t0; e < kD*8*512; e += stride) {
      int dd = e >> 12, r = e & 4095;
      int f = r >> 9, l = (r >> 3) & 63, j = r & 7;
      int row = l & 31;
      int col = f*16 + ((l >> 5) << 3) + j;
      wfimg[e] = (f16)((row == 0) ? gWf[dd*kH + pif(col)] : 0.f);
    }
    return;
  }

  // ---------------- fc path ----------------
  const int bn = blockIdx.x * 128;
  const int tid = threadIdx.x, wave = tid >> 6, lane = tid & 63;
  const int l31 = lane & 31, h5 = lane >> 5;
  const int wbase = wave << 6;
  const int n = bn + wave*32 + l31;

  #pragma unroll
  for (int i = 0; i < 8; ++i)
    lds_dma16(fW1 + (size_t)(i*256 + tid)*8, wbuf + (size_t)(i*256 + wbase)*8);
  #pragma unroll
  for (int i = 0; i < 8; ++i) {
    int idx = i*256 + tid;
    if (idx < 1920)   // wave-uniform: 1920 = 7*256 + 128 (wave boundary)
      lds_dma16(fWf + (size_t)idx*8, wbuf + (size_t)(2048 + i*256 + wbase)*8);
  }

  const float* erow = emb + (size_t)n*kE + h5*8;
  f16x8 eB[6];
  #pragma unroll
  for (int c = 0; c < 6; ++c) {
    float4 a = *(const float4*)(erow + c*16);
    float4 bb = *(const float4*)(erow + c*16 + 4);
    eB[c] = cvt8(a, bb);
  }
  __syncthreads();                              // B1: wbuf ready

  f32x16 zero = {};
  f32x16 acc[4] = {zero, zero, zero, zero};
  f16x8 wpre[3][4];
  #pragma unroll
  for (int t = 0; t < 4; ++t) wpre[0][t] = gfrag(fW0, t, lane);
  #pragma unroll
  for (int t = 0; t < 4; ++t) wpre[1][t] = gfrag(fW0, 4+t, lane);
  #pragma unroll
  for (int c = 0; c < 6; ++c) {
    if (c + 2 < 6)
      #pragma unroll
      for (int t = 0; t < 4; ++t) wpre[(c+2)%3][t] = gfrag(fW0, (c+2)*4+t, lane);
    #pragma unroll
    for (int t = 0; t < 4; ++t)
      acc[t] = MFMA_(wpre[c%3][t], eB[c], acc[t], 0, 0, 0);
  }

  f16x8 hq[4][2];
  #pragma unroll
  for (int t = 0; t < 4; ++t)
    #pragma unroll
    for (int q = 0; q < 4; ++q) {
      float4 b4 = *(const float4*)(b0 + t*32 + q*8 + h5*4);
      const float* bp = (const float*)&b4;
      #pragma unroll
      for (int e = 0; e < 4; ++e) {
        float z = acc[t][q*4+e] + bp[e];
        hq[t][q>>1][(q&1)*4+e] = (f16)fmaxf(z, SLOPE_*z);
      }
    }

  #pragma unroll
  for (int t = 0; t < 4; ++t) acc[t] = zero;
  #pragma unroll
  for (int c = 0; c < 8; ++c) {
    f16x8 bP = hq[c>>1][c&1];
    #pragma unroll
    for (int t = 0; t < 4; ++t)
      acc[t] = MFMA_(*(const f16x8*)(wbuf + (size_t)(c*4+t)*512 + lane*8),
                     bP, acc[t], 0, 0, 0);
  }
  #pragma unroll
  for (int t = 0; t < 4; ++t)
    #pragma unroll
    for (int q = 0; q < 4; ++q) {
      float4 b4 = *(const float4*)(b1 + t*32 + q*8 + h5*4);
      const float* bp = (const float*)&b4;
      #pragma unroll
      for (int e = 0; e < 4; ++e) {
        float z = acc[t][q*4+e] + bp[e];
        hq[t][q>>1][(q&1)*4+e] = (f16)fmaxf(z, SLOPE_*z);
      }
    }

  #pragma unroll
  for (int t = 0; t < 4; ++t) acc[t] = zero;
  #pragma unroll
  for (int c = 0; c < 8; ++c) {
    f16x8 bP = hq[c>>1][c&1];
    #pragma unroll
    for (int t = 0; t < 4; ++t) {
      int f = c*4 + t;
      f16x8 a = (f < 30) ? *(const f16x8*)(wbuf + (size_t)(32 + f)*512 + lane*8)
                         : gfrag(fWf, f, lane);
      acc[t] = MFMA_(a, bP, acc[t], 0, 0, 0);
    }
  }
  #pragma unroll
  for (int t = 0; t < 4; ++t)
    #pragma unroll
    for (int q = 0; q < 4; ++q) {
      float4 b4 = *(const float4*)(bf + t*32 + q*8 + h5*4);
      const float* bp = (const float*)&b4;
      #pragma unroll
      for (int e = 0; e < 4; ++e)
        hq[t][q>>1][(q&1)*4+e] = (f16)(acc[t][q*4+e] + bp[e]);
    }
  #pragma unroll
  for (int c = 0; c < 8; ++c)
    *(f16x8*)(out + (size_t)n*kH + c*16 + h5*8) = hq[c>>1][c&1];
}

// ==== g_mlp fwd + JVP (R5 structure; epilogues use shared multiplier) =======
// XCD-octave swizzle (FETCH 40.7->8.6 MB verified) + streamed L0 operands +
// w144 via LDS + 1-ahead A-frag double buffer. 128 VGPR + 128 AGPR, 2 w/SIMD.
// Epilogue: s = z>=0 ? 1.0 : 0.2 shared between P and T (z*1.0f==z bit-exact)
// -> one cmp+sel per element instead of two muls+sels.
__global__ __launch_bounds__(256, 2) void g_kernel(
    const float* __restrict__ x, const f16* __restrict__ embh,
    const f16* __restrict__ W0img, const f16* __restrict__ W1img,
    const f16* __restrict__ W2img, const f16* __restrict__ wfimg,
    const float* __restrict__ w144buf, const float* __restrict__ gbf,
    float* __restrict__ resid, float* __restrict__ logdet)
{
  __shared__ f16 wbuf[72*512];                 // W1 frags 0..35, W2 frags 36..71
  __shared__ float wlds[kH];                   // w144 for this d (f32)
  __shared__ float part[8];
  const int bid = blockIdx.x;
  const int c8 = bid & 7;                      // XCD under id%8 round-robin
  const int q  = bid >> 3;                     // 0..255
  const int d  = q & 7;
  const int bx = (q >> 3)*8 + c8;              // row-chunk 0..255
  if (bx >= kN/128) return;                    // 8 ghost blocks (bx==255)
  const int bn = bx*128;
  const int tid = threadIdx.x, wave = tid >> 6, lane = tid & 63;
  const int l31 = lane & 31, h5 = lane >> 5;
  const int wbase = wave << 6;
  const int n = bn + wave*32 + l31;
  const int b = n / kTM, tt = n - b*kTM;

  const f16* W0d = W0img + (size_t)d*40*512;
  const f16* W1d = W1img + (size_t)d*36*512;
  const f16* W2d = W2img + (size_t)d*36*512;
  const f16* WFd = wfimg + (size_t)d*8*512;

  // ---- stage W1 + W2 via LDS-DMA; w144 via plain ds_write
  #pragma unroll
  for (int i = 0; i < 9; ++i)
    lds_dma16(W1d + (size_t)(i*256 + tid)*8, wbuf + (size_t)(i*256 + wbase)*8);
  #pragma unroll
  for (int i = 0; i < 9; ++i)
    lds_dma16(W2d + (size_t)(i*256 + tid)*8,
              wbuf + (size_t)(36*512) + (size_t)(i*256 + wbase)*8);
  if (tid < kH) wlds[tid] = w144buf[d*kH + tid];

  // x-derived inputs
  const float* xp = x + ((size_t)b*kT + tt + h5)*kD;
  float4 xa = *(const float4*)xp;
  float4 xb = *(const float4*)(xp + 4);
  f16x8 f8 = cvt8(xa, xb);
  const float xxv = x[((size_t)b*kT + tt + 2)*kD + d];
  f16x8 zeroh = {};
  f16x8 xb9 = zeroh;                 // chunk 9: [xx, 1, 0...] on h5==0 lanes
  if (!h5) { xb9[0] = (f16)xxv; xb9[1] = (f16)1.f; }
  f16x8 bC = zeroh;                  // bias chunk: [1, 0...] on h5==0 lanes
  if (!h5) bC[0] = (f16)1.f;

  f32x16 zero = {};
  f32x16 accP[4] = {zero, zero, zero, zero};

  // ---- P L0: stream embh B-chunks 2-ahead (L2-resident after octave swizzle)
  // and triple-buffer W0 A-fragments.
  const f16* erow = embh + (size_t)n*kH + h5*8;
  f16x8 eS[3];
  eS[0] = *(const f16x8*)(erow + 0*16);
  eS[1] = *(const f16x8*)(erow + 1*16);
  f16x8 wpre[3][4];
  #pragma unroll
  for (int t = 0; t < 4; ++t) wpre[0][t] = gfrag(W0d, t, lane);
  #pragma unroll
  for (int t = 0; t < 4; ++t) wpre[1][t] = gfrag(W0d, 4+t, lane);
  #pragma unroll
  for (int c = 0; c < 10; ++c) {
    if (c + 2 < 8)
      eS[(c+2)%3] = *(const f16x8*)(erow + (c+2)*16);
    if (c + 2 < 10)
      #pragma unroll
      for (int t = 0; t < 4; ++t)
        wpre[(c+2)%3][t] = gfrag(W0d, (c+2)*4 + t, lane);
    f16x8 bOp = (c < 8) ? eS[c%3] : ((c == 8) ? f8 : xb9);
    #pragma unroll
    for (int t = 0; t < 4; ++t)
      accP[t] = MFMA_(wpre[c%3][t], bOp, accP[t], 0, 0, 0);
  }
  __syncthreads();   // B1: wbuf DMA drained + wlds visible (before epilogue)

  // L0 epilogue: w144 from LDS per-t; shared multiplier select (bit-exact)
  f16x8 hqP[4][2], hqT[4][2];
  #pragma unroll
  for (int t = 0; t < 4; ++t) {
    float4 w4[4];
    #pragma unroll
    for (int q2 = 0; q2 < 4; ++q2)
      w4[q2] = *(const float4*)(wlds + t*32 + q2*8 + h5*4);
    #pragma unroll
    for (int q2 = 0; q2 < 4; ++q2) {
      const float* wp = (const float*)&w4[q2];
      #pragma unroll
      for (int e = 0; e < 4; ++e) {
        float z = accP[t][q2*4+e];
        float s = (z >= 0.f) ? 1.f : SLOPE_;
        hqP[t][q2>>1][(q2&1)*4+e] = (f16)(z * s);
        hqT[t][q2>>1][(q2&1)*4+e] = (f16)(wp[e] * s);
      }
    }
  }

  // ---- L1 (LDS frags 0..35; bias via chunk 8, P only); A-frags 1-ahead
  f32x16 accT[4] = {zero, zero, zero, zero};
  #pragma unroll
  for (int t = 0; t < 4; ++t) accP[t] = zero;
  f16x8 abuf[2][4];
  #pragma unroll
  for (int t = 0; t < 4; ++t)
    abuf[0][t] = *(const f16x8*)(wbuf + (size_t)t*512 + lane*8);
  #pragma unroll
  for (int c = 0; c < 9; ++c) {
    if (c < 8)
      #pragma unroll
      for (int t = 0; t < 4; ++t)
        abuf[(c+1)&1][t] =
            *(const f16x8*)(wbuf + (size_t)((c+1)*4+t)*512 + lane*8);
    f16x8 bP = (c < 8) ? hqP[c>>1][c&1] : bC;
    #pragma unroll
    for (int t = 0; t < 4; ++t) {
      accP[t] = MFMA_(abuf[c&1][t], bP, accP[t], 0, 0, 0);
      if (c < 8)
        accT[t] = MFMA_(abuf[c&1][t], hqT[c>>1][c&1], accT[t], 0, 0, 0);
    }
  }
  #pragma unroll
  for (int t = 0; t < 4; ++t)
    #pragma unroll
    for (int q2 = 0; q2 < 4; ++q2)
      #pragma unroll
      for (int e = 0; e < 4; ++e) {
        float z = accP[t][q2*4+e];
        float tv = accT[t][q2*4+e];
        float s = (z >= 0.f) ? 1.f : SLOPE_;
        hqP[t][q2>>1][(q2&1)*4+e] = (f16)(z * s);
        hqT[t][q2>>1][(q2&1)*4+e] = (f16)(tv * s);
      }

  // ---- L2 (LDS frags 36..71; bias via chunk 8, P only); A-frags 1-ahead
  #pragma unroll
  for (int t = 0; t < 4; ++t) { accP[t] = zero; accT[t] = zero; }
  #pragma unroll
  for (int t = 0; t < 4; ++t)
    abuf[0][t] = *(const f16x8*)(wbuf + (size_t)(36 + t)*512 + lane*8);
  #pragma unroll
  for (int c = 0; c < 9; ++c) {
    if (c < 8)
      #pragma unroll
      for (int t = 0; t < 4; ++t)
        abuf[(c+1)&1][t] =
            *(const f16x8*)(wbuf + (size_t)(36 + (c+1)*4+t)*512 + lane*8);
    f16x8 bP = (c < 8) ? hqP[c>>1][c&1] : bC;
    #pragma unroll
    for (int t = 0; t < 4; ++t) {
      accP[t] = MFMA_(abuf[c&1][t], bP, accP[t], 0, 0, 0);
      if (c < 8)
        accT[t] = MFMA_(abuf[c&1][t], hqT[c>>1][c&1], accT[t], 0, 0, 0);
    }
  }
  #pragma unroll
  for (int t = 0; t < 4; ++t)
    #pragma unroll
    for (int q2 = 0; q2 < 4; ++q2)
      #pragma unroll
      for (int e = 0; e < 4; ++e) {
        float z = accP[t][q2*4+e];
        float tv = accT[t][q2*4+e];
        float s = (z >= 0.f) ? 1.f : SLOPE_;
        hqP[t][q2>>1][(q2&1)*4+e] = (f16)(z * s);
        hqT[t][q2>>1][(q2&1)*4+e] = (f16)(tv * s);
      }

  // ---- final dots via MFMA (wf in output-row 0 of wfimg)
  f16x8 wff[8];
  #pragma unroll
  for (int c = 0; c < 8; ++c) wff[c] = gfrag(WFd, c, lane);
  accP[0] = zero; accT[0] = zero;
  #pragma unroll
  for (int c = 0; c < 8; ++c) {
    accP[0] = MFMA_(wff[c], hqP[c>>1][c&1], accP[0], 0, 0, 0);
    accT[0] = MFMA_(wff[c], hqT[c>>1][c&1], accT[0], 0, 0, 0);
  }
  // row 0 result lives in reg 0 of lanes 0..31 (col = lane)
  float llog = 0.f;
  if (!h5) {
    float p  = accP[0][0];
    float tp = accT[0][0];
    resid[(size_t)n*kD + d] = p + gbf[d];
    llog = 0.69314718055994531f * __log2f(fabsf(tp));
  }
  const int bfirst = bn / kTM;
  float s0 = (b == bfirst) ? llog : 0.f;
  float s1 = llog - s0;
  #pragma unroll
  for (int off = 32; off > 0; off >>= 1) {
    s0 += __shfl_down(s0, off, 64);
    s1 += __shfl_down(s1, off, 64);
  }
  if (lane == 0) { part[wave*2] = s0; part[wave*2 + 1] = s1; }
  __syncthreads();                              // B2
  if (tid == 0) {
    float S0 = part[0] + part[2] + part[4] + part[6];
    float S1 = part[1] + part[3] + part[5] + part[7];
    atomicAdd(&logdet[bfirst], S0);
    if (S1 != 0.f) atomicAdd(&logdet[bfirst + 1], S1);
  }
}

extern "C" void kernel_launch(void* const* d_in, const int* in_sizes, int n_in,
                              void* d_out, int out_size, void* d_ws, size_t ws_size,
                              hipStream_t stream) {
  const float* x    = (const float*)d_in[0];
  const float* emb  = (const float*)d_in[1];
  const float* fcW0 = (const float*)d_in[2];
  const float* fcb0 = (const float*)d_in[3];
  const float* fcW1 = (const float*)d_in[4];
  const float* fcb1 = (const float*)d_in[5];
  const float* fcWf = (const float*)d_in[6];
  const float* fcbf = (const float*)d_in[7];
  const float* gW0  = (const float*)d_in[8];
  const float* gb0  = (const float*)d_in[9];
  const float* gW1  = (const float*)d_in[10];
  const float* gb1  = (const float*)d_in[11];
  const float* gW2  = (const float*)d_in[12];
  const float* gb2  = (const float*)d_in[13];
  const float* gWf  = (const float*)d_in[14];
  const float* gbf  = (const float*)d_in[15];
  float* out = (float*)d_out;
  float* logdet = out + (size_t)kN * kD;

  char* ws = (char*)d_ws;
  f16*   embh    = (f16*)ws;    ws += (size_t)kN*kH*2;
  f16*   W0img   = (f16*)ws;    ws += (size_t)kD*40*512*2;
  f16*   W1img   = (f16*)ws;    ws += (size_t)kD*36*512*2;
  f16*   W2img   = (f16*)ws;    ws += (size_t)kD*36*512*2;
  f16*   wfimg   = (f16*)ws;    ws += (size_t)kD*8*512*2;
  f16*   fW0img  = (f16*)ws;    ws += (size_t)24*512*2;
  f16*   fW1img  = (f16*)ws;    ws += (size_t)32*512*2;
  f16*   fWfimg  = (f16*)ws;    ws += (size_t)32*512*2;
  float* w144buf = (float*)ws;

  cvt_fc_kernel<<<256, 256, 0, stream>>>(fcW0, fcW1, fcWf, gW0,
                                         fW0img, fW1img, fWfimg,
                                         w144buf, logdet);
  fc_cvtg_kernel<<<kFCB + 256, 256, 0, stream>>>(
      emb, fW0img, fW1img, fWfimg, fcb0, fcb1, fcbf, embh,
      gW0, gW1, gW2, gb0, gb1, gb2, gWf,
      W0img, W1img, W2img, wfimg);
  g_kernel<<<2048, 256, 0, stream>>>(
      x, embh, W0img, W1img, W2img, wfimg, w144buf, gbf, out, logdet);
}

// Round 10
// 150.919 us; speedup vs baseline: 1.0315x; 1.0315x over previous
//
#include <hip/hip_runtime.h>
#include <math.h>

typedef _Float16 f16;
typedef _Float16 f16x4 __attribute__((ext_vector_type(4)));
typedef _Float16 f16x8 __attribute__((ext_vector_type(8)));
typedef float f32x16 __attribute__((ext_vector_type(16)));

#define MFMA_ __builtin_amdgcn_mfma_f32_32x32x16_f16
#define SLOPE_ 0.2f

constexpr int kB = 64, kT = 512, kD = 8, kH = 128, kE = 96;
constexpr int kFG = 145, kTM = 510, kN = kB * kTM;   // 32640 = 255*128
constexpr int kFCB = kN / 128;                       // 255 fc blocks

// k-permutation absorbed into weight images so next-layer B-fragments are the
// held C/D quads verbatim. For k<128 this swaps bits 2<->3 region-wise; any
// aligned 4-col group maps to 4 CONSECUTIVE dest cols (j&3 preserved).
__device__ __forceinline__ int pif(int k) {
  if (k >= 128) return k;
  int c = k >> 4, s = (k >> 3) & 1, j = k & 7;
  return ((c >> 1) << 5) | ((c & 1) << 4) | ((j >> 2) << 3) | (s << 2) | (j & 3);
}

// fragment-linear images: frag f = 64 lanes x 16 B contiguous.
__device__ __forceinline__ f16x8 gfrag(const f16* img, int f, int lane) {
  return *(const f16x8*)(img + (size_t)f*512 + lane*8);
}

// async global->LDS DMA, 16B per lane (wave-uniform LDS base + lane*16).
__device__ __forceinline__ void lds_dma16(const f16* g, f16* l) {
  __builtin_amdgcn_global_load_lds(
      (const __attribute__((address_space(1))) void*)g,
      (__attribute__((address_space(3))) void*)l, 16, 0, 0);
}

__device__ __forceinline__ f16x8 cvt8(float4 a, float4 b) {
  f16x8 v;
  v[0]=(f16)a.x; v[1]=(f16)a.y; v[2]=(f16)a.z; v[3]=(f16)a.w;
  v[4]=(f16)b.x; v[5]=(f16)b.y; v[6]=(f16)b.z; v[7]=(f16)b.w;
  return v;
}

// ========= fc-weight pre-convert: f32 row-major -> f16 fragment-linear ======
template<int NF, int SK, int PERM>
__device__ __forceinline__ void cvt_img(const float* __restrict__ src,
                                        f16* __restrict__ dst, int nd,
                                        int t0, int stride) {
  const int per_d = NF * 512;
  for (int e = t0; e < nd * per_d; e += stride) {
    int dd = e / per_d, r = e - dd * per_d;
    int f = r >> 9, l = (r >> 3) & 63, j = r & 7;
    int c = f >> 2, t = f & 3;
    int row = t*32 + (l & 31);
    int col = c*16 + ((l >> 5) << 3) + j;
    if (PERM) col = pif(col);
    dst[e] = (f16)src[((size_t)dd*kH + row)*SK + col];
  }
}

// Small kernel: only what fc_kernel needs, plus w144/logdet init.
__global__ __launch_bounds__(256) void cvt_fc_kernel(
    const float* __restrict__ fcW0, const float* __restrict__ fcW1,
    const float* __restrict__ fcWf, const float* __restrict__ gW0,
    f16* __restrict__ fW0img, f16* __restrict__ fW1img, f16* __restrict__ fWfimg,
    float* __restrict__ w144buf, float* __restrict__ logdet)
{
  const int stride = gridDim.x * 256;
  const int t0 = blockIdx.x*256 + threadIdx.x;
  cvt_img<24, kE , 0>(fcW0, fW0img, 1, t0, stride);
  cvt_img<32, kH , 1>(fcW1, fW1img, 1, t0, stride);
  cvt_img<32, kH , 1>(fcWf, fWfimg, 1, t0, stride);
  for (int i = t0; i < kD*kH; i += stride)
    w144buf[i] = gW0[(size_t)i*kFG + 144];
  if (t0 < kB) logdet[t0] = 0.f;
}

// ===== fused dispatch: blocks 0..254 run fc_mlp; blocks 255..510 convert the
// g-weight images. Conversion 4-col vectorized: pif maps aligned 4-col groups
// to consecutive dest cols -> float4 loads + single 8B f16x4 stores. ========
__global__ __launch_bounds__(256, 2) void fc_cvtg_kernel(
    const float* __restrict__ emb,
    const f16* __restrict__ fW0, const f16* __restrict__ fW1,
    const f16* __restrict__ fWf,
    const float* __restrict__ b0, const float* __restrict__ b1,
    const float* __restrict__ bf, f16* __restrict__ out,
    const float* __restrict__ gW0, const float* __restrict__ gW1,
    const float* __restrict__ gW2,
    const float* __restrict__ gb0, const float* __restrict__ gb1,
    const float* __restrict__ gb2, const float* __restrict__ gWf,
    f16* __restrict__ W0img, f16* __restrict__ W1img, f16* __restrict__ W2img,
    f16* __restrict__ wfimg)
{
  __shared__ f16 wbuf[62*512];                 // fW1 frags 0..31, fWf frags 0..29

  if (blockIdx.x >= kFCB) {
    // ---------------- cvt-g path (no LDS, no barriers) ----------------
    const int t0 = (blockIdx.x - kFCB)*256 + threadIdx.x;
    const int stride = (gridDim.x - kFCB) * 256;

    // W1/W2 main cols 0..127: 4-col groups. kH*kH/4 = 4096 groups per d.
    for (int idx = t0; idx < kD*kH*kH/4; idx += stride) {
      int d = idx >> 12, r = idx & 4095;
      int row = r >> 5, colS = (r & 31) * 4;
      float4 v1 = *(const float4*)(gW1 + ((size_t)d*kH + row)*kH + colS);
      float4 v2 = *(const float4*)(gW2 + ((size_t)d*kH + row)*kH + colS);
      int colD = pif(colS);                    // 4 consecutive dest cols
      int c = colD >> 4, hb = (colD >> 3) & 1, j = colD & 7;
      int e = d*36*512 + (c*4 + (row>>5))*512 + (hb*32 + (row&31))*8 + j;
      f16x4 h1; h1[0]=(f16)v1.x; h1[1]=(f16)v1.y; h1[2]=(f16)v1.z; h1[3]=(f16)v1.w;
      f16x4 h2; h2[0]=(f16)v2.x; h2[1]=(f16)v2.y; h2[2]=(f16)v2.z; h2[3]=(f16)v2.w;
      *(f16x4*)(W1img + e) = h1;
      *(f16x4*)(W2img + e) = h2;
    }
    // W1/W2 slab frags 32..35 (dest cols 128..143): bias at col 128, else 0.
    for (int idx = t0; idx < kD*4*512; idx += stride) {
      int d = idx >> 11, r = idx & 2047;
      int t = r >> 9, l = (r >> 3) & 63, j = r & 7;
      int hb = l >> 5, l31 = l & 31;
      int colD = 128 + hb*8 + j;
      int row = t*32 + l31;
      float v1 = (colD == 128) ? gb1[d*kH + row] : 0.f;
      float v2 = (colD == 128) ? gb2[d*kH + row] : 0.f;
      int e = d*36*512 + (32 + t)*512 + l*8 + j;
      W1img[e] = (f16)v1;
      W2img[e] = (f16)v2;
    }
    // W0 main cols 0..143: 4-col groups (36 per row). Row stride 145 floats
    // -> scalar loads (4B-aligned), same cache line; 8B vector store.
    for (int idx = t0; idx < kD*kH*36; idx += stride) {
      int d = idx / (kH*36), r = idx - d*(kH*36);
      int row = r / 36, colS = (r - row*36) * 4;
      const float* p = gW0 + ((size_t)d*kH + row)*kFG + colS;
      float a0 = p[0], a1 = p[1], a2 = p[2], a3 = p[3];
      int colD = (colS < 128) ? pif(colS) : colS;
      int c = colD >> 4, hb = (colD >> 3) & 1, j = colD & 7;
      int e = d*40*512 + (c*4 + (row>>5))*512 + (hb*32 + (row&31))*8 + j;
      f16x4 h; h[0]=(f16)a0; h[1]=(f16)a1; h[2]=(f16)a2; h[3]=(f16)a3;
      *(f16x4*)(W0img + e) = h;
    }
    // W0 slab frags 36..39 (dest cols 144..159): w144, bias, zeros.
    for (int idx = t0; idx < kD*4*512; idx += stride) {
      int d = idx >> 11, r = idx & 2047;
      int t = r >> 9, l = (r >> 3) & 63, j = r & 7;
      int hb = l >> 5, l31 = l & 31;
      int colD = 144 + hb*8 + j;
      int row = t*32 + l31;
      float v = (colD == 144) ? gW0[((size_t)d*kH + row)*kFG + 144]
              : (colD == 145) ? gb0[d*kH + row] : 0.f;
      int e = d*40*512 + (36 + t)*512 + l*8 + j;
      W0img[e] = (f16)v;
    }
    // wfimg: 8 frags/d, wf in output-row 0 only, pi-ordered cols (tiny).
    for (int e = t0; e < kD*8*512; e += stride) {
      int dd = e >> 12, r = e & 4095;
      int f = r >> 9, l = (r >> 3) & 63, j = r & 7;
      int row = l & 31;
      int col = f*16 + ((l >> 5) << 3) + j;
      wfimg[e] = (f16)((row == 0) ? gWf[dd*kH + pif(col)] : 0.f);
    }
    return;
  }

  // ---------------- fc path ----------------
  const int bn = blockIdx.x * 128;
  const int tid = threadIdx.x, wave = tid >> 6, lane = tid & 63;
  const int l31 = lane & 31, h5 = lane >> 5;
  const int wbase = wave << 6;
  const int n = bn + wave*32 + l31;

  #pragma unroll
  for (int i = 0; i < 8; ++i)
    lds_dma16(fW1 + (size_t)(i*256 + tid)*8, wbuf + (size_t)(i*256 + wbase)*8);
  #pragma unroll
  for (int i = 0; i < 8; ++i) {
    int idx = i*256 + tid;
    if (idx < 1920)   // wave-uniform: 1920 = 7*256 + 128 (wave boundary)
      lds_dma16(fWf + (size_t)idx*8, wbuf + (size_t)(2048 + i*256 + wbase)*8);
  }

  const float* erow = emb + (size_t)n*kE + h5*8;
  f16x8 eB[6];
  #pragma unroll
  for (int c = 0; c < 6; ++c) {
    float4 a = *(const float4*)(erow + c*16);
    float4 bb = *(const float4*)(erow + c*16 + 4);
    eB[c] = cvt8(a, bb);
  }
  __syncthreads();                              // B1: wbuf ready

  f32x16 zero = {};
  f32x16 acc[4] = {zero, zero, zero, zero};
  f16x8 wpre[3][4];
  #pragma unroll
  for (int t = 0; t < 4; ++t) wpre[0][t] = gfrag(fW0, t, lane);
  #pragma unroll
  for (int t = 0; t < 4; ++t) wpre[1][t] = gfrag(fW0, 4+t, lane);
  #pragma unroll
  for (int c = 0; c < 6; ++c) {
    if (c + 2 < 6)
      #pragma unroll
      for (int t = 0; t < 4; ++t) wpre[(c+2)%3][t] = gfrag(fW0, (c+2)*4+t, lane);
    #pragma unroll
    for (int t = 0; t < 4; ++t)
      acc[t] = MFMA_(wpre[c%3][t], eB[c], acc[t], 0, 0, 0);
  }

  f16x8 hq[4][2];
  #pragma unroll
  for (int t = 0; t < 4; ++t)
    #pragma unroll
    for (int q = 0; q < 4; ++q) {
      float4 b4 = *(const float4*)(b0 + t*32 + q*8 + h5*4);
      const float* bp = (const float*)&b4;
      #pragma unroll
      for (int e = 0; e < 4; ++e) {
        float z = acc[t][q*4+e] + bp[e];
        hq[t][q>>1][(q&1)*4+e] = (f16)fmaxf(z, SLOPE_*z);
      }
    }

  #pragma unroll
  for (int t = 0; t < 4; ++t) acc[t] = zero;
  #pragma unroll
  for (int c = 0; c < 8; ++c) {
    f16x8 bP = hq[c>>1][c&1];
    #pragma unroll
    for (int t = 0; t < 4; ++t)
      acc[t] = MFMA_(*(const f16x8*)(wbuf + (size_t)(c*4+t)*512 + lane*8),
                     bP, acc[t], 0, 0, 0);
  }
  #pragma unroll
  for (int t = 0; t < 4; ++t)
    #pragma unroll
    for (int q = 0; q < 4; ++q) {
      float4 b4 = *(const float4*)(b1 + t*32 + q*8 + h5*4);
      const float* bp = (const float*)&b4;
      #pragma unroll
      for (int e = 0; e < 4; ++e) {
        float z = acc[t][q*4+e] + bp[e];
        hq[t][q>>1][(q&1)*4+e] = (f16)fmaxf(z, SLOPE_*z);
      }
    }

  #pragma unroll
  for (int t = 0; t < 4; ++t) acc[t] = zero;
  #pragma unroll
  for (int c = 0; c < 8; ++c) {
    f16x8 bP = hq[c>>1][c&1];
    #pragma unroll
    for (int t = 0; t < 4; ++t) {
      int f = c*4 + t;
      f16x8 a = (f < 30) ? *(const f16x8*)(wbuf + (size_t)(32 + f)*512 + lane*8)
                         : gfrag(fWf, f, lane);
      acc[t] = MFMA_(a, bP, acc[t], 0, 0, 0);
    }
  }
  #pragma unroll
  for (int t = 0; t < 4; ++t)
    #pragma unroll
    for (int q = 0; q < 4; ++q) {
      float4 b4 = *(const float4*)(bf + t*32 + q*8 + h5*4);
      const float* bp = (const float*)&b4;
      #pragma unroll
      for (int e = 0; e < 4; ++e)
        hq[t][q>>1][(q&1)*4+e] = (f16)(acc[t][q*4+e] + bp[e]);
    }
  #pragma unroll
  for (int c = 0; c < 8; ++c)
    *(f16x8*)(out + (size_t)n*kH + c*16 + h5*8) = hq[c>>1][c&1];
}

// ==== g_mlp fwd + JVP (R8 known-best, select-form epilogues) ================
// XCD-octave swizzle (FETCH 40.7->8.6 MB verified) + streamed L0 operands +
// w144 via LDS + 1-ahead A-frag double buffer. 128 VGPR + 128 AGPR, 2 w/SIMD.
// Structural plateau: joint P+T state binds the register cap at 32-row MFMA
// granularity and 72KB LDS binds blocks/CU at 2; scheduling levers (reg-slack,
// dbuf, stagger, epilogue trim) all measured null (R5/R8/R9).
__global__ __launch_bounds__(256, 2) void g_kernel(
    const float* __restrict__ x, const f16* __restrict__ embh,
    const f16* __restrict__ W0img, const f16* __restrict__ W1img,
    const f16* __restrict__ W2img, const f16* __restrict__ wfimg,
    const float* __restrict__ w144buf, const float* __restrict__ gbf,
    float* __restrict__ resid, float* __restrict__ logdet)
{
  __shared__ f16 wbuf[72*512];                 // W1 frags 0..35, W2 frags 36..71
  __shared__ float wlds[kH];                   // w144 for this d (f32)
  __shared__ float part[8];
  const int bid = blockIdx.x;
  const int c8 = bid & 7;                      // XCD under id%8 round-robin
  const int q  = bid >> 3;                     // 0..255
  const int d  = q & 7;
  const int bx = (q >> 3)*8 + c8;              // row-chunk 0..255
  if (bx >= kN/128) return;                    // 8 ghost blocks (bx==255)
  const int bn = bx*128;
  const int tid = threadIdx.x, wave = tid >> 6, lane = tid & 63;
  const int l31 = lane & 31, h5 = lane >> 5;
  const int wbase = wave << 6;
  const int n = bn + wave*32 + l31;
  const int b = n / kTM, tt = n - b*kTM;

  const f16* W0d = W0img + (size_t)d*40*512;
  const f16* W1d = W1img + (size_t)d*36*512;
  const f16* W2d = W2img + (size_t)d*36*512;
  const f16* WFd = wfimg + (size_t)d*8*512;

  // ---- stage W1 + W2 via LDS-DMA; w144 via plain ds_write
  #pragma unroll
  for (int i = 0; i < 9; ++i)
    lds_dma16(W1d + (size_t)(i*256 + tid)*8, wbuf + (size_t)(i*256 + wbase)*8);
  #pragma unroll
  for (int i = 0; i < 9; ++i)
    lds_dma16(W2d + (size_t)(i*256 + tid)*8,
              wbuf + (size_t)(36*512) + (size_t)(i*256 + wbase)*8);
  if (tid < kH) wlds[tid] = w144buf[d*kH + tid];

  // x-derived inputs
  const float* xp = x + ((size_t)b*kT + tt + h5)*kD;
  float4 xa = *(const float4*)xp;
  float4 xb = *(const float4*)(xp + 4);
  f16x8 f8 = cvt8(xa, xb);
  const float xxv = x[((size_t)b*kT + tt + 2)*kD + d];
  f16x8 zeroh = {};
  f16x8 xb9 = zeroh;                 // chunk 9: [xx, 1, 0...] on h5==0 lanes
  if (!h5) { xb9[0] = (f16)xxv; xb9[1] = (f16)1.f; }
  f16x8 bC = zeroh;                  // bias chunk: [1, 0...] on h5==0 lanes
  if (!h5) bC[0] = (f16)1.f;

  f32x16 zero = {};
  f32x16 accP[4] = {zero, zero, zero, zero};

  // ---- P L0: stream embh B-chunks 2-ahead (L2-resident after octave swizzle)
  // and triple-buffer W0 A-fragments.
  const f16* erow = embh + (size_t)n*kH + h5*8;
  f16x8 eS[3];
  eS[0] = *(const f16x8*)(erow + 0*16);
  eS[1] = *(const f16x8*)(erow + 1*16);
  f16x8 wpre[3][4];
  #pragma unroll
  for (int t = 0; t < 4; ++t) wpre[0][t] = gfrag(W0d, t, lane);
  #pragma unroll
  for (int t = 0; t < 4; ++t) wpre[1][t] = gfrag(W0d, 4+t, lane);
  #pragma unroll
  for (int c = 0; c < 10; ++c) {
    if (c + 2 < 8)
      eS[(c+2)%3] = *(const f16x8*)(erow + (c+2)*16);
    if (c + 2 < 10)
      #pragma unroll
      for (int t = 0; t < 4; ++t)
        wpre[(c+2)%3][t] = gfrag(W0d, (c+2)*4 + t, lane);
    f16x8 bOp = (c < 8) ? eS[c%3] : ((c == 8) ? f8 : xb9);
    #pragma unroll
    for (int t = 0; t < 4; ++t)
      accP[t] = MFMA_(wpre[c%3][t], bOp, accP[t], 0, 0, 0);
  }
  __syncthreads();   // B1: wbuf DMA drained + wlds visible (before epilogue)

  // L0 epilogue: w144 from LDS per-t (broadcast reads, conflict-free);
  // tangent seed = mask * w144
  f16x8 hqP[4][2], hqT[4][2];
  #pragma unroll
  for (int t = 0; t < 4; ++t) {
    float4 w4[4];
    #pragma unroll
    for (int q2 = 0; q2 < 4; ++q2)
      w4[q2] = *(const float4*)(wlds + t*32 + q2*8 + h5*4);
    #pragma unroll
    for (int q2 = 0; q2 < 4; ++q2) {
      const float* wp = (const float*)&w4[q2];
      #pragma unroll
      for (int e = 0; e < 4; ++e) {
        float z = accP[t][q2*4+e];
        bool pos = (z >= 0.f);
        hqP[t][q2>>1][(q2&1)*4+e] = (f16)(pos ? z : SLOPE_*z);
        hqT[t][q2>>1][(q2&1)*4+e] = (f16)(pos ? wp[e] : SLOPE_*wp[e]);
      }
    }
  }

  // ---- L1 (LDS frags 0..35; bias via chunk 8, P only); A-frags 1-ahead
  f32x16 accT[4] = {zero, zero, zero, zero};
  #pragma unroll
  for (int t = 0; t < 4; ++t) accP[t] = zero;
  f16x8 abuf[2][4];
  #pragma unroll
  for (int t = 0; t < 4; ++t)
    abuf[0][t] = *(const f16x8*)(wbuf + (size_t)t*512 + lane*8);
  #pragma unroll
  for (int c = 0; c < 9; ++c) {
    if (c < 8)
      #pragma unroll
      for (int t = 0; t < 4; ++t)
        abuf[(c+1)&1][t] =
            *(const f16x8*)(wbuf + (size_t)((c+1)*4+t)*512 + lane*8);
    f16x8 bP = (c < 8) ? hqP[c>>1][c&1] : bC;
    #pragma unroll
    for (int t = 0; t < 4; ++t) {
      accP[t] = MFMA_(abuf[c&1][t], bP, accP[t], 0, 0, 0);
      if (c < 8)
        accT[t] = MFMA_(abuf[c&1][t], hqT[c>>1][c&1], accT[t], 0, 0, 0);
    }
  }
  #pragma unroll
  for (int t = 0; t < 4; ++t)
    #pragma unroll
    for (int q2 = 0; q2 < 4; ++q2)
      #pragma unroll
      for (int e = 0; e < 4; ++e) {
        float z = accP[t][q2*4+e];
        float tv = accT[t][q2*4+e];
        bool pos = (z >= 0.f);
        hqP[t][q2>>1][(q2&1)*4+e] = (f16)(pos ? z : SLOPE_*z);
        hqT[t][q2>>1][(q2&1)*4+e] = (f16)(pos ? tv : SLOPE_*tv);
      }

  // ---- L2 (LDS frags 36..71; bias via chunk 8, P only); A-frags 1-ahead
  #pragma unroll
  for (int t = 0; t < 4; ++t) { accP[t] = zero; accT[t] = zero; }
  #pragma unroll
  for (int t = 0; t < 4; ++t)
    abuf[0][t] = *(const f16x8*)(wbuf + (size_t)(36 + t)*512 + lane*8);
  #pragma unroll
  for (int c = 0; c < 9; ++c) {
    if (c < 8)
      #pragma unroll
      for (int t = 0; t < 4; ++t)
        abuf[(c+1)&1][t] =
            *(const f16x8*)(wbuf + (size_t)(36 + (c+1)*4+t)*512 + lane*8);
    f16x8 bP = (c < 8) ? hqP[c>>1][c&1] : bC;
    #pragma unroll
    for (int t = 0; t < 4; ++t) {
      accP[t] = MFMA_(abuf[c&1][t], bP, accP[t], 0, 0, 0);
      if (c < 8)
        accT[t] = MFMA_(abuf[c&1][t], hqT[c>>1][c&1], accT[t], 0, 0, 0);
    }
  }
  #pragma unroll
  for (int t = 0; t < 4; ++t)
    #pragma unroll
    for (int q2 = 0; q2 < 4; ++q2)
      #pragma unroll
      for (int e = 0; e < 4; ++e) {
        float z = accP[t][q2*4+e];
        float tv = accT[t][q2*4+e];
        bool pos = (z >= 0.f);
        hqP[t][q2>>1][(q2&1)*4+e] = (f16)(pos ? z : SLOPE_*z);
        hqT[t][q2>>1][(q2&1)*4+e] = (f16)(pos ? tv : SLOPE_*tv);
      }

  // ---- final dots via MFMA (wf in output-row 0 of wfimg)
  f16x8 wff[8];
  #pragma unroll
  for (int c = 0; c < 8; ++c) wff[c] = gfrag(WFd, c, lane);
  accP[0] = zero; accT[0] = zero;
  #pragma unroll
  for (int c = 0; c < 8; ++c) {
    accP[0] = MFMA_(wff[c], hqP[c>>1][c&1], accP[0], 0, 0, 0);
    accT[0] = MFMA_(wff[c], hqT[c>>1][c&1], accT[0], 0, 0, 0);
  }
  // row 0 result lives in reg 0 of lanes 0..31 (col = lane)
  float llog = 0.f;
  if (!h5) {
    float p  = accP[0][0];
    float tp = accT[0][0];
    resid[(size_t)n*kD + d] = p + gbf[d];
    llog = 0.69314718055994531f * __log2f(fabsf(tp));
  }
  const int bfirst = bn / kTM;
  float s0 = (b == bfirst) ? llog : 0.f;
  float s1 = llog - s0;
  #pragma unroll
  for (int off = 32; off > 0; off >>= 1) {
    s0 += __shfl_down(s0, off, 64);
    s1 += __shfl_down(s1, off, 64);
  }
  if (lane == 0) { part[wave*2] = s0; part[wave*2 + 1] = s1; }
  __syncthreads();                              // B2
  if (tid == 0) {
    float S0 = part[0] + part[2] + part[4] + part[6];
    float S1 = part[1] + part[3] + part[5] + part[7];
    atomicAdd(&logdet[bfirst], S0);
    if (S1 != 0.f) atomicAdd(&logdet[bfirst + 1], S1);
  }
}

extern "C" void kernel_launch(void* const* d_in, const int* in_sizes, int n_in,
                              void* d_out, int out_size, void* d_ws, size_t ws_size,
                              hipStream_t stream) {
  const float* x    = (const float*)d_in[0];
  const float* emb  = (const float*)d_in[1];
  const float* fcW0 = (const float*)d_in[2];
  const float* fcb0 = (const float*)d_in[3];
  const float* fcW1 = (const float*)d_in[4];
  const float* fcb1 = (const float*)d_in[5];
  const float* fcWf = (const float*)d_in[6];
  const float* fcbf = (const float*)d_in[7];
  const float* gW0  = (const float*)d_in[8];
  const float* gb0  = (const float*)d_in[9];
  const float* gW1  = (const float*)d_in[10];
  const float* gb1  = (const float*)d_in[11];
  const float* gW2  = (const float*)d_in[12];
  const float* gb2  = (const float*)d_in[13];
  const float* gWf  = (const float*)d_in[14];
  const float* gbf  = (const float*)d_in[15];
  float* out = (float*)d_out;
  float* logdet = out + (size_t)kN * kD;

  char* ws = (char*)d_ws;
  f16*   embh    = (f16*)ws;    ws += (size_t)kN*kH*2;
  f16*   W0img   = (f16*)ws;    ws += (size_t)kD*40*512*2;
  f16*   W1img   = (f16*)ws;    ws += (size_t)kD*36*512*2;
  f16*   W2img   = (f16*)ws;    ws += (size_t)kD*36*512*2;
  f16*   wfimg   = (f16*)ws;    ws += (size_t)kD*8*512*2;
  f16*   fW0img  = (f16*)ws;    ws += (size_t)24*512*2;
  f16*   fW1img  = (f16*)ws;    ws += (size_t)32*512*2;
  f16*   fWfimg  = (f16*)ws;    ws += (size_t)32*512*2;
  float* w144buf = (float*)ws;

  cvt_fc_kernel<<<256, 256, 0, stream>>>(fcW0, fcW1, fcWf, gW0,
                                         fW0img, fW1img, fWfimg,
                                         w144buf, logdet);
  fc_cvtg_kernel<<<kFCB + 256, 256, 0, stream>>>(
      emb, fW0img, fW1img, fWfimg, fcb0, fcb1, fcbf, embh,
      gW0, gW1, gW2, gb0, gb1, gb2, gWf,
      W0img, W1img, W2img, wfimg);
  g_kernel<<<2048, 256, 0, stream>>>(
      x, embh, W0img, W1img, W2img, wfimg, w144buf, gbf, out, logdet);
}